// Round 12
// baseline (315.822 us; speedup 1.0000x reference)
//
#include <hip/hip_runtime.h>
#include <math.h>

#define V 100000
#define D 128
#define A 64
#define LVLS 3
#define NN 20000
#define KK 16
#define BK 32
#define TM 96        // row tile: As[96*34]+Bs[32*132] = 29,952 B -> 2 blocks/CU (R7-measured)
#define ASTRIDE 34   // 32 + 2 pad -> measured 0 conflicts (R1/R5/R7)
#define BSTW 132     // 128 + 4 pad (merged B tile; R6/R7-measured 0 conflicts)
#define HALF1 50016  // 521 blocks * 96 rows; second dispatch covers the rest
#define BKC 32       // commit K-chunk: 8 threads x 16B = FULL 128B line per row per chunk
#define ASTC 34
#define BSTC 68
#define PSTRIDE 128  // projAll row: [0,64)=node-half (W1+b), [64,128)=neighbor-half (W2)

// MERGED projection (R7-passed, 66 us total): C[V][128] = Leaf @ Wcomb[128][128],
// fused Leaf->out copy. Split into TWO half-grid dispatches (r0base) so each is
// ~34 us -> attn_kernel surfaces in the rocprof top-5 for the first time.
__global__ __launch_bounds__(256, 2)
void projall_kernel(const float* __restrict__ Leaf, const float* __restrict__ Watt,
                    const float* __restrict__ batt, float* __restrict__ projAll,
                    float* __restrict__ outp, int r0base) {
    __shared__ float As[TM * ASTRIDE];   // 13.1 KB
    __shared__ float Bs[BK * BSTW];      // 16.9 KB
    int t = threadIdx.x;
    int tx = t & 15, ty = t >> 4;
    int r0 = r0base + blockIdx.x * TM;

    const float* srcp[3];
    int rg[3];
#pragma unroll
    for (int jj = 0; jj < 3; ++jj) {
        int r = r0 + (t >> 3) + 32 * jj;
        rg[jj] = r;
        int rr = r < V ? r : V - 1;
        srcp[jj] = Leaf + (size_t)rr * D + ((t & 7) << 2);
    }
    int bc = (t & 31) << 2;
    int bk0 = t >> 5;
    const float* bbase = (bc < 64) ? (Watt + bc)
                                   : (Watt + (size_t)128 * A + (bc - 64));

    float4 bv = *(const float4*)(batt + 4 * tx);
    float accA[6][4], accB[6][4];
#pragma unroll
    for (int i = 0; i < 6; ++i) {
        accA[i][0] = bv.x; accA[i][1] = bv.y; accA[i][2] = bv.z; accA[i][3] = bv.w;
        accB[i][0] = 0.f;  accB[i][1] = 0.f;  accB[i][2] = 0.f;  accB[i][3] = 0.f;
    }

    for (int k0 = 0; k0 < D; k0 += BK) {
#pragma unroll
        for (int jj = 0; jj < 3; ++jj) {
            float4 v = *(const float4*)(srcp[jj] + k0);
            *(float4*)&As[((t >> 3) + 32 * jj) * ASTRIDE + ((t & 7) << 2)] = v;
            if (rg[jj] < V)
                *(float4*)(outp + (size_t)rg[jj] * D + k0 + ((t & 7) << 2)) = v;
        }
#pragma unroll
        for (int ss = 0; ss < 4; ++ss)
            *(float4*)&Bs[(bk0 + 8 * ss) * BSTW + bc] =
                *(const float4*)(bbase + (size_t)(k0 + bk0 + 8 * ss) * A);
        __syncthreads();
#pragma unroll
        for (int kc = 0; kc < BK; kc += 4) {
            float4 b0 = *(const float4*)&Bs[(kc + 0) * BSTW + 4 * tx];
            float4 b1 = *(const float4*)&Bs[(kc + 1) * BSTW + 4 * tx];
            float4 b2 = *(const float4*)&Bs[(kc + 2) * BSTW + 4 * tx];
            float4 b3 = *(const float4*)&Bs[(kc + 3) * BSTW + 4 * tx];
            float4 c0 = *(const float4*)&Bs[(kc + 0) * BSTW + 64 + 4 * tx];
            float4 c1 = *(const float4*)&Bs[(kc + 1) * BSTW + 64 + 4 * tx];
            float4 c2 = *(const float4*)&Bs[(kc + 2) * BSTW + 64 + 4 * tx];
            float4 c3 = *(const float4*)&Bs[(kc + 3) * BSTW + 64 + 4 * tx];
#pragma unroll
            for (int i = 0; i < 6; ++i) {
                float4 a = *(const float4*)&As[(6 * ty + i) * ASTRIDE + kc];
                accA[i][0] = fmaf(a.x, b0.x, accA[i][0]);
                accA[i][0] = fmaf(a.y, b1.x, accA[i][0]);
                accA[i][0] = fmaf(a.z, b2.x, accA[i][0]);
                accA[i][0] = fmaf(a.w, b3.x, accA[i][0]);
                accA[i][1] = fmaf(a.x, b0.y, accA[i][1]);
                accA[i][1] = fmaf(a.y, b1.y, accA[i][1]);
                accA[i][1] = fmaf(a.z, b2.y, accA[i][1]);
                accA[i][1] = fmaf(a.w, b3.y, accA[i][1]);
                accA[i][2] = fmaf(a.x, b0.z, accA[i][2]);
                accA[i][2] = fmaf(a.y, b1.z, accA[i][2]);
                accA[i][2] = fmaf(a.z, b2.z, accA[i][2]);
                accA[i][2] = fmaf(a.w, b3.z, accA[i][2]);
                accA[i][3] = fmaf(a.x, b0.w, accA[i][3]);
                accA[i][3] = fmaf(a.y, b1.w, accA[i][3]);
                accA[i][3] = fmaf(a.z, b2.w, accA[i][3]);
                accA[i][3] = fmaf(a.w, b3.w, accA[i][3]);
                accB[i][0] = fmaf(a.x, c0.x, accB[i][0]);
                accB[i][0] = fmaf(a.y, c1.x, accB[i][0]);
                accB[i][0] = fmaf(a.z, c2.x, accB[i][0]);
                accB[i][0] = fmaf(a.w, c3.x, accB[i][0]);
                accB[i][1] = fmaf(a.x, c0.y, accB[i][1]);
                accB[i][1] = fmaf(a.y, c1.y, accB[i][1]);
                accB[i][1] = fmaf(a.z, c2.y, accB[i][1]);
                accB[i][1] = fmaf(a.w, c3.y, accB[i][1]);
                accB[i][2] = fmaf(a.x, c0.z, accB[i][2]);
                accB[i][2] = fmaf(a.y, c1.z, accB[i][2]);
                accB[i][2] = fmaf(a.z, c2.z, accB[i][2]);
                accB[i][2] = fmaf(a.w, c3.z, accB[i][2]);
                accB[i][3] = fmaf(a.x, c0.w, accB[i][3]);
                accB[i][3] = fmaf(a.y, c1.w, accB[i][3]);
                accB[i][3] = fmaf(a.z, c2.w, accB[i][3]);
                accB[i][3] = fmaf(a.w, c3.w, accB[i][3]);
            }
        }
        __syncthreads();
    }

#pragma unroll
    for (int i = 0; i < 6; ++i) {
        int gr = r0 + 6 * ty + i;
        if (gr < V) {
            float4 oA = make_float4(accA[i][0], accA[i][1], accA[i][2], accA[i][3]);
            float4 oB = make_float4(accB[i][0], accB[i][1], accB[i][2], accB[i][3]);
            *(float4*)(projAll + (size_t)gr * PSTRIDE + 4 * tx) = oA;
            *(float4*)(projAll + (size_t)gr * PSTRIDE + 64 + 4 * tx) = oB;
        }
    }
}

// Tile commit, BK=32: the out-scatter now writes FULL 128B lines per row per
// chunk (old BK=16 wrote 64B halves -> fetch-on-write RMW, the R2 bug pattern).
// 4 chunks x 2 barriers (was 8 x 2), register-prefetch, LDS 17.4 KB -> 3 blocks/CU.
__global__ __launch_bounds__(256, 3)
void commit_kernel(const float* __restrict__ tmp, const float* __restrict__ Wmat,
                   const int* __restrict__ nodes_l, const int* __restrict__ claim,
                   float* __restrict__ outp, float* __restrict__ projAll, int do_proj) {
    __shared__ float As[64 * ASTC];   // 8.7 KB
    __shared__ float Bs[BKC * BSTC];  // 8.7 KB
    int t = threadIdx.x;
    int tx = t & 15, ty = t >> 4;     // ty 0..15, 4 rows each
    int r0 = blockIdx.x * 64;

    int ar = t >> 3;                  // 0..31 (two staged rows per thread)
    int ak = (t & 7) << 2;            // 0..28: 8 threads cover one row's 32 floats
    const float* asrc[2];
    int vr[2], win[2];
#pragma unroll
    for (int jj = 0; jj < 2; ++jj) {
        int r = r0 + ar + 32 * jj;
        int rr = r < NN ? r : NN - 1;
        asrc[jj] = tmp + (size_t)rr * D + ak;
        int v = nodes_l[rr];
        vr[jj] = v;
        win[jj] = (r < NN) && (claim[v] == rr);   // last-occurrence-wins
    }

    float acc[4][4];
#pragma unroll
    for (int i = 0; i < 4; ++i) {
        acc[i][0] = 0.f; acc[i][1] = 0.f; acc[i][2] = 0.f; acc[i][3] = 0.f;
    }

    // prefetch chunk 0
    float4 pa0 = *(const float4*)(asrc[0]);
    float4 pa1 = *(const float4*)(asrc[1]);
    float4 pb0 = make_float4(0.f, 0.f, 0.f, 0.f), pb1 = pb0;
    int bk0 = t >> 4, bc0 = (t & 15) << 2;        // s0 = t      -> k-rows 0..15
    int bk1 = bk0 + 16;                           // s1 = t+256  -> k-rows 16..31
    if (do_proj) {
        pb0 = *(const float4*)(Wmat + (size_t)bk0 * A + bc0);
        pb1 = *(const float4*)(Wmat + (size_t)bk1 * A + bc0);
    }

    for (int k0 = 0; k0 < D; k0 += BKC) {
        if (k0) __syncthreads();
        *(float4*)&As[(ar +  0) * ASTC + ak] = pa0;
        *(float4*)&As[(ar + 32) * ASTC + ak] = pa1;
        if (do_proj) {
            *(float4*)&Bs[bk0 * BSTC + bc0] = pb0;
            *(float4*)&Bs[bk1 * BSTC + bc0] = pb1;
        }
        if (win[0]) *(float4*)(outp + (size_t)vr[0] * D + k0 + ak) = pa0;  // full line
        if (win[1]) *(float4*)(outp + (size_t)vr[1] * D + k0 + ak) = pa1;
        __syncthreads();
        int kn = k0 + BKC;
        if (kn < D) {
            pa0 = *(const float4*)(asrc[0] + kn);
            pa1 = *(const float4*)(asrc[1] + kn);
            if (do_proj) {
                pb0 = *(const float4*)(Wmat + (size_t)(kn + bk0) * A + bc0);
                pb1 = *(const float4*)(Wmat + (size_t)(kn + bk1) * A + bc0);
            }
        }
        if (do_proj) {
#pragma unroll
            for (int kc = 0; kc < BKC; kc += 4) {
                float4 b0 = *(const float4*)&Bs[(kc + 0) * BSTC + 4 * tx];
                float4 b1 = *(const float4*)&Bs[(kc + 1) * BSTC + 4 * tx];
                float4 b2 = *(const float4*)&Bs[(kc + 2) * BSTC + 4 * tx];
                float4 b3 = *(const float4*)&Bs[(kc + 3) * BSTC + 4 * tx];
#pragma unroll
                for (int i = 0; i < 4; ++i) {
                    float4 a = *(const float4*)&As[(4 * ty + i) * ASTC + kc];
                    acc[i][0] = fmaf(a.x, b0.x, acc[i][0]);
                    acc[i][0] = fmaf(a.y, b1.x, acc[i][0]);
                    acc[i][0] = fmaf(a.z, b2.x, acc[i][0]);
                    acc[i][0] = fmaf(a.w, b3.x, acc[i][0]);
                    acc[i][1] = fmaf(a.x, b0.y, acc[i][1]);
                    acc[i][1] = fmaf(a.y, b1.y, acc[i][1]);
                    acc[i][1] = fmaf(a.z, b2.y, acc[i][1]);
                    acc[i][1] = fmaf(a.w, b3.y, acc[i][1]);
                    acc[i][2] = fmaf(a.x, b0.z, acc[i][2]);
                    acc[i][2] = fmaf(a.y, b1.z, acc[i][2]);
                    acc[i][2] = fmaf(a.z, b2.z, acc[i][2]);
                    acc[i][2] = fmaf(a.w, b3.z, acc[i][2]);
                    acc[i][3] = fmaf(a.x, b0.w, acc[i][3]);
                    acc[i][3] = fmaf(a.y, b1.w, acc[i][3]);
                    acc[i][3] = fmaf(a.z, b2.w, acc[i][3]);
                    acc[i][3] = fmaf(a.w, b3.w, acc[i][3]);
                }
            }
        }
    }

    if (do_proj) {
#pragma unroll
        for (int i = 0; i < 4; ++i) {
            int gr = r0 + 4 * ty + i;
            if (gr < NN) {
                int v = nodes_l[gr];
                if (claim[v] == gr) {
                    float4 o = make_float4(acc[i][0], acc[i][1], acc[i][2], acc[i][3]);
                    *(float4*)(projAll + (size_t)v * PSTRIDE + 64 + 4 * tx) = o;
                }
            }
        }
    }
}

// One wave per node (R11-passed: in-loop PV loads, launch_bounds(256,8)).
__global__ __launch_bounds__(256, 8)
void attn_kernel(const float* __restrict__ Wc, const float* __restrict__ projAll,
                 const int* __restrict__ nodes_l, const int* __restrict__ neigh,
                 const float* __restrict__ maskp, const float* __restrict__ weightp,
                 const float* __restrict__ v_att, float* __restrict__ tmp) {
    int lane = threadIdx.x & 63;
    int n = blockIdx.x * 4 + (threadIdx.x >> 6);
    int k16 = lane & 15, q = lane >> 4;

    int   vnode = nodes_l[n];
    int   nbk = neigh[n * KK + k16];
    float wv  = weightp[n * KK + k16];
    float mk  = maskp[n * KK + k16];

    const float* npr = projAll + (size_t)vnode * PSTRIDE + q * 16;
    const float* var = v_att + q * 16;
    const float* pr  = projAll + (size_t)nbk * PSTRIDE + 64 + q * 16;

    float part = 0.f;
#pragma unroll
    for (int j = 0; j < 16; j += 4) {
        float4 npv = *(const float4*)(npr + j);
        float4 vav = *(const float4*)(var + j);
        float4 pv  = *(const float4*)(pr + j);
        float x;
        x = npv.x + pv.x; x = fmaxf(x, 0.01f * x); part = fmaf(x, vav.x, part);
        x = npv.y + pv.y; x = fmaxf(x, 0.01f * x); part = fmaf(x, vav.y, part);
        x = npv.z + pv.z; x = fmaxf(x, 0.01f * x); part = fmaf(x, vav.z, part);
        x = npv.w + pv.w; x = fmaxf(x, 0.01f * x); part = fmaf(x, vav.w, part);
    }
    part += __shfl_xor(part, 16);
    part += __shfl_xor(part, 32);
    float pre = part + mk;

    float mp = pre, mw = wv;
#pragma unroll
    for (int off = 8; off >= 1; off >>= 1) {
        mp = fmaxf(mp, __shfl_xor(mp, off));
        mw = fmaxf(mw, __shfl_xor(mw, off));
    }
    float ep = __expf(pre - mp), ew = __expf(wv - mw);
    float sp = ep, sw = ew;
#pragma unroll
    for (int off = 8; off >= 1; off >>= 1) {
        sp += __shfl_xor(sp, off);
        sw += __shfl_xor(sw, off);
    }
    float att = (ep / sp) * (ew / sw);

    int half = lane >> 5, li = lane & 31;
    float ax = 0.f, ay = 0.f, az = 0.f, aw = 0.f;
#pragma unroll
    for (int m = 0; m < 8; ++m) {
        int src = 2 * m + half;
        int nb   = __shfl(nbk, src);
        float ak = __shfl(att, src);
        float4 e = *(const float4*)&Wc[(size_t)nb * D + 4 * li];
        ax = fmaf(e.x, ak, ax); ay = fmaf(e.y, ak, ay);
        az = fmaf(e.z, ak, az); aw = fmaf(e.w, ak, aw);
    }
    ax += __shfl_xor(ax, 32); ay += __shfl_xor(ay, 32);
    az += __shfl_xor(az, 32); aw += __shfl_xor(aw, 32);
    if (half == 0) {
        float4 o = make_float4(ax, ay, az, aw);
        *(float4*)&tmp[(size_t)n * D + 4 * li] = o;
    }
}

// claims for ALL levels in one pass (depends only on nodes input)
__global__ void amax3_kernel(const int* __restrict__ nodes, int* __restrict__ claims, int total) {
    int i = blockIdx.x * 256 + threadIdx.x;
    if (i < total) {
        int lvl = i / NN, pos = i - lvl * NN;
        atomicMax(&claims[(size_t)lvl * V + nodes[i]], pos);
    }
}

extern "C" void kernel_launch(void* const* d_in, const int* in_sizes, int n_in,
                              void* d_out, int out_size, void* d_ws, size_t ws_size,
                              hipStream_t stream) {
    const float* Leaf    = (const float*)d_in[0];
    const int*   nodes   = (const int*)d_in[1];
    const int*   neigh   = (const int*)d_in[2];
    const float* masks   = (const float*)d_in[3];
    const float* weights = (const float*)d_in[4];
    const float* Watt    = (const float*)d_in[5];
    const float* batt    = (const float*)d_in[6];
    const float* vatt    = (const float*)d_in[7];
    float* out = (float*)d_out;

    char* ws = (char*)d_ws;
    float* projAll = (float*)ws;                                      // V*128
    float* tmp     = (float*)(ws + (size_t)V * PSTRIDE * 4);          // NN*D
    int*   claims  = (int*)(ws + (size_t)(V * PSTRIDE + NN * D) * 4); // LVLS*V

    hipMemsetAsync(claims, 0xFF, (size_t)LVLS * V * sizeof(int), stream);  // -1
    amax3_kernel<<<(LVLS * NN + 255) / 256, 256, 0, stream>>>(nodes, claims, LVLS * NN);
    // merged projection + out copy, split into two half-grids (measurement aid:
    // each ~34 us < attn so attn surfaces in rocprof top-5)
    projall_kernel<<<HALF1 / TM, 256, 0, stream>>>(Leaf, Watt, batt, projAll, out, 0);
    projall_kernel<<<(V - HALF1 + TM - 1) / TM, 256, 0, stream>>>(
        Leaf, Watt, batt, projAll, out, HALF1);

    for (int l = 0; l < LVLS; ++l) {
        const int* nodes_l = nodes + l * NN;
        attn_kernel<<<NN / 4, 256, 0, stream>>>(out, projAll, nodes_l,
                                                neigh + (size_t)l * NN * KK,
                                                masks + (size_t)l * NN * KK,
                                                weights + (size_t)l * NN * KK, vatt, tmp);
        commit_kernel<<<(NN + 63) / 64, 256, 0, stream>>>(
            tmp, Watt + (size_t)D * A, nodes_l, claims + (size_t)l * V, out, projAll,
            (l + 1 < LVLS) ? 1 : 0);
    }
}

// Round 13
// 295.771 us; speedup vs baseline: 1.0678x; 1.0678x over previous
//
#include <hip/hip_runtime.h>
#include <math.h>

#define V 100000
#define D 128
#define A 64
#define LVLS 3
#define NN 20000
#define KK 16
#define BK 32
#define TM 96        // row tile: As[96*34]+Bs[32*132] = 29,952 B -> 2 blocks/CU (R7-measured)
#define ASTRIDE 34   // 32 + 2 pad -> measured 0 conflicts (R1/R5/R7)
#define BSTW 132     // 128 + 4 pad (merged B tile; R6/R7-measured 0 conflicts)
#define BKC 32       // commit K-chunk: 8 threads x 16B = FULL 128B line per row per chunk
#define ASTC 34
#define BSTC 68
#define PSTRIDE 128  // projAll row: [0,64)=node-half (W1+b), [64,128)=neighbor-half (W2)

// MERGED projection (R7/R11-passed, 67 us): C[V][128] = Leaf @ Wcomb[128][128],
// one pass, fused Leaf->out copy. Single dispatch (R12's half-split cost +17 us).
__global__ __launch_bounds__(256, 2)
void projall_kernel(const float* __restrict__ Leaf, const float* __restrict__ Watt,
                    const float* __restrict__ batt, float* __restrict__ projAll,
                    float* __restrict__ outp) {
    __shared__ float As[TM * ASTRIDE];   // 13.1 KB
    __shared__ float Bs[BK * BSTW];      // 16.9 KB
    int t = threadIdx.x;
    int tx = t & 15, ty = t >> 4;
    int r0 = blockIdx.x * TM;

    const float* srcp[3];
    int rg[3];
#pragma unroll
    for (int jj = 0; jj < 3; ++jj) {
        int r = r0 + (t >> 3) + 32 * jj;
        rg[jj] = r;
        int rr = r < V ? r : V - 1;
        srcp[jj] = Leaf + (size_t)rr * D + ((t & 7) << 2);
    }
    int bc = (t & 31) << 2;
    int bk0 = t >> 5;
    const float* bbase = (bc < 64) ? (Watt + bc)
                                   : (Watt + (size_t)128 * A + (bc - 64));

    float4 bv = *(const float4*)(batt + 4 * tx);
    float accA[6][4], accB[6][4];
#pragma unroll
    for (int i = 0; i < 6; ++i) {
        accA[i][0] = bv.x; accA[i][1] = bv.y; accA[i][2] = bv.z; accA[i][3] = bv.w;
        accB[i][0] = 0.f;  accB[i][1] = 0.f;  accB[i][2] = 0.f;  accB[i][3] = 0.f;
    }

    for (int k0 = 0; k0 < D; k0 += BK) {
#pragma unroll
        for (int jj = 0; jj < 3; ++jj) {
            float4 v = *(const float4*)(srcp[jj] + k0);
            *(float4*)&As[((t >> 3) + 32 * jj) * ASTRIDE + ((t & 7) << 2)] = v;
            if (rg[jj] < V)
                *(float4*)(outp + (size_t)rg[jj] * D + k0 + ((t & 7) << 2)) = v;
        }
#pragma unroll
        for (int ss = 0; ss < 4; ++ss)
            *(float4*)&Bs[(bk0 + 8 * ss) * BSTW + bc] =
                *(const float4*)(bbase + (size_t)(k0 + bk0 + 8 * ss) * A);
        __syncthreads();
#pragma unroll
        for (int kc = 0; kc < BK; kc += 4) {
            float4 b0 = *(const float4*)&Bs[(kc + 0) * BSTW + 4 * tx];
            float4 b1 = *(const float4*)&Bs[(kc + 1) * BSTW + 4 * tx];
            float4 b2 = *(const float4*)&Bs[(kc + 2) * BSTW + 4 * tx];
            float4 b3 = *(const float4*)&Bs[(kc + 3) * BSTW + 4 * tx];
            float4 c0 = *(const float4*)&Bs[(kc + 0) * BSTW + 64 + 4 * tx];
            float4 c1 = *(const float4*)&Bs[(kc + 1) * BSTW + 64 + 4 * tx];
            float4 c2 = *(const float4*)&Bs[(kc + 2) * BSTW + 64 + 4 * tx];
            float4 c3 = *(const float4*)&Bs[(kc + 3) * BSTW + 64 + 4 * tx];
#pragma unroll
            for (int i = 0; i < 6; ++i) {
                float4 a = *(const float4*)&As[(6 * ty + i) * ASTRIDE + kc];
                accA[i][0] = fmaf(a.x, b0.x, accA[i][0]);
                accA[i][0] = fmaf(a.y, b1.x, accA[i][0]);
                accA[i][0] = fmaf(a.z, b2.x, accA[i][0]);
                accA[i][0] = fmaf(a.w, b3.x, accA[i][0]);
                accA[i][1] = fmaf(a.x, b0.y, accA[i][1]);
                accA[i][1] = fmaf(a.y, b1.y, accA[i][1]);
                accA[i][1] = fmaf(a.z, b2.y, accA[i][1]);
                accA[i][1] = fmaf(a.w, b3.y, accA[i][1]);
                accA[i][2] = fmaf(a.x, b0.z, accA[i][2]);
                accA[i][2] = fmaf(a.y, b1.z, accA[i][2]);
                accA[i][2] = fmaf(a.z, b2.z, accA[i][2]);
                accA[i][2] = fmaf(a.w, b3.z, accA[i][2]);
                accA[i][3] = fmaf(a.x, b0.w, accA[i][3]);
                accA[i][3] = fmaf(a.y, b1.w, accA[i][3]);
                accA[i][3] = fmaf(a.z, b2.w, accA[i][3]);
                accA[i][3] = fmaf(a.w, b3.w, accA[i][3]);
                accB[i][0] = fmaf(a.x, c0.x, accB[i][0]);
                accB[i][0] = fmaf(a.y, c1.x, accB[i][0]);
                accB[i][0] = fmaf(a.z, c2.x, accB[i][0]);
                accB[i][0] = fmaf(a.w, c3.x, accB[i][0]);
                accB[i][1] = fmaf(a.x, c0.y, accB[i][1]);
                accB[i][1] = fmaf(a.y, c1.y, accB[i][1]);
                accB[i][1] = fmaf(a.z, c2.y, accB[i][1]);
                accB[i][1] = fmaf(a.w, c3.y, accB[i][1]);
                accB[i][2] = fmaf(a.x, c0.z, accB[i][2]);
                accB[i][2] = fmaf(a.y, c1.z, accB[i][2]);
                accB[i][2] = fmaf(a.z, c2.z, accB[i][2]);
                accB[i][2] = fmaf(a.w, c3.z, accB[i][2]);
                accB[i][3] = fmaf(a.x, c0.w, accB[i][3]);
                accB[i][3] = fmaf(a.y, c1.w, accB[i][3]);
                accB[i][3] = fmaf(a.z, c2.w, accB[i][3]);
                accB[i][3] = fmaf(a.w, c3.w, accB[i][3]);
            }
        }
        __syncthreads();
    }

#pragma unroll
    for (int i = 0; i < 6; ++i) {
        int gr = r0 + 6 * ty + i;
        if (gr < V) {
            float4 oA = make_float4(accA[i][0], accA[i][1], accA[i][2], accA[i][3]);
            float4 oB = make_float4(accB[i][0], accB[i][1], accB[i][2], accB[i][3]);
            *(float4*)(projAll + (size_t)gr * PSTRIDE + 4 * tx) = oA;
            *(float4*)(projAll + (size_t)gr * PSTRIDE + 64 + 4 * tx) = oB;
        }
    }
}

// Tile commit, 32-ROW tiles: 625 blocks (~2.4/CU) vs old 313 (1.2/CU, half the
// chip idle + 2x imbalance -> measured-inferred ~35us/level, 8x its traffic
// floor). Half the per-block serial chain; LDS 13.1KB -> 4 blocks/CU at (256,4).
// BKC=32: out-scatter writes full 128B lines (R2's RMW lesson). Micro 2x4.
__global__ __launch_bounds__(256, 4)
void commit_kernel(const float* __restrict__ tmp, const float* __restrict__ Wmat,
                   const int* __restrict__ nodes_l, const int* __restrict__ claim,
                   float* __restrict__ outp, float* __restrict__ projAll, int do_proj) {
    __shared__ float As[32 * ASTC];   // 4.4 KB
    __shared__ float Bs[BKC * BSTC];  // 8.7 KB
    int t = threadIdx.x;
    int tx = t & 15, ty = t >> 4;     // ty 0..15, 2 rows each
    int r0 = blockIdx.x * 32;

    int ar = t >> 3;                  // 0..31: one staged row per thread
    int ak = (t & 7) << 2;            // 8 threads cover one row's 32-float chunk
    int r = r0 + ar;
    int rr = r < NN ? r : NN - 1;
    const float* asrc = tmp + (size_t)rr * D + ak;
    int vrow = nodes_l[rr];
    int win = (r < NN) && (claim[vrow] == rr);   // last-occurrence-wins

    float acc[2][4];
#pragma unroll
    for (int i = 0; i < 2; ++i) {
        acc[i][0] = 0.f; acc[i][1] = 0.f; acc[i][2] = 0.f; acc[i][3] = 0.f;
    }

    // prefetch chunk 0
    float4 pa = *(const float4*)(asrc);
    float4 pb0 = make_float4(0.f, 0.f, 0.f, 0.f), pb1 = pb0;
    int bk0 = t >> 4, bc0 = (t & 15) << 2;   // k-rows 0..15 and 16..31
    int bk1 = bk0 + 16;
    if (do_proj) {
        pb0 = *(const float4*)(Wmat + (size_t)bk0 * A + bc0);
        pb1 = *(const float4*)(Wmat + (size_t)bk1 * A + bc0);
    }

    for (int k0 = 0; k0 < D; k0 += BKC) {
        if (k0) __syncthreads();
        *(float4*)&As[ar * ASTC + ak] = pa;
        if (do_proj) {
            *(float4*)&Bs[bk0 * BSTC + bc0] = pb0;
            *(float4*)&Bs[bk1 * BSTC + bc0] = pb1;
        }
        if (win) *(float4*)(outp + (size_t)vrow * D + k0 + ak) = pa;  // full line
        __syncthreads();
        int kn = k0 + BKC;
        if (kn < D) {
            pa = *(const float4*)(asrc + kn);
            if (do_proj) {
                pb0 = *(const float4*)(Wmat + (size_t)(kn + bk0) * A + bc0);
                pb1 = *(const float4*)(Wmat + (size_t)(kn + bk1) * A + bc0);
            }
        }
        if (do_proj) {
#pragma unroll
            for (int kc = 0; kc < BKC; kc += 4) {
                float4 b0 = *(const float4*)&Bs[(kc + 0) * BSTC + 4 * tx];
                float4 b1 = *(const float4*)&Bs[(kc + 1) * BSTC + 4 * tx];
                float4 b2 = *(const float4*)&Bs[(kc + 2) * BSTC + 4 * tx];
                float4 b3 = *(const float4*)&Bs[(kc + 3) * BSTC + 4 * tx];
#pragma unroll
                for (int i = 0; i < 2; ++i) {
                    float4 a = *(const float4*)&As[(2 * ty + i) * ASTC + kc];
                    acc[i][0] = fmaf(a.x, b0.x, acc[i][0]);
                    acc[i][0] = fmaf(a.y, b1.x, acc[i][0]);
                    acc[i][0] = fmaf(a.z, b2.x, acc[i][0]);
                    acc[i][0] = fmaf(a.w, b3.x, acc[i][0]);
                    acc[i][1] = fmaf(a.x, b0.y, acc[i][1]);
                    acc[i][1] = fmaf(a.y, b1.y, acc[i][1]);
                    acc[i][1] = fmaf(a.z, b2.y, acc[i][1]);
                    acc[i][1] = fmaf(a.w, b3.y, acc[i][1]);
                    acc[i][2] = fmaf(a.x, b0.z, acc[i][2]);
                    acc[i][2] = fmaf(a.y, b1.z, acc[i][2]);
                    acc[i][2] = fmaf(a.z, b2.z, acc[i][2]);
                    acc[i][2] = fmaf(a.w, b3.z, acc[i][2]);
                    acc[i][3] = fmaf(a.x, b0.w, acc[i][3]);
                    acc[i][3] = fmaf(a.y, b1.w, acc[i][3]);
                    acc[i][3] = fmaf(a.z, b2.w, acc[i][3]);
                    acc[i][3] = fmaf(a.w, b3.w, acc[i][3]);
                }
            }
        }
    }

    if (do_proj) {
#pragma unroll
        for (int i = 0; i < 2; ++i) {
            int gr = r0 + 2 * ty + i;
            if (gr < NN) {
                int v = nodes_l[gr];
                if (claim[v] == gr) {
                    float4 o = make_float4(acc[i][0], acc[i][1], acc[i][2], acc[i][3]);
                    *(float4*)(projAll + (size_t)v * PSTRIDE + 64 + 4 * tx) = o;
                }
            }
        }
    }
}

// One wave per node (R11-passed: in-loop PV loads, launch_bounds(256,8)).
__global__ __launch_bounds__(256, 8)
void attn_kernel(const float* __restrict__ Wc, const float* __restrict__ projAll,
                 const int* __restrict__ nodes_l, const int* __restrict__ neigh,
                 const float* __restrict__ maskp, const float* __restrict__ weightp,
                 const float* __restrict__ v_att, float* __restrict__ tmp) {
    int lane = threadIdx.x & 63;
    int n = blockIdx.x * 4 + (threadIdx.x >> 6);
    int k16 = lane & 15, q = lane >> 4;

    int   vnode = nodes_l[n];
    int   nbk = neigh[n * KK + k16];
    float wv  = weightp[n * KK + k16];
    float mk  = maskp[n * KK + k16];

    const float* npr = projAll + (size_t)vnode * PSTRIDE + q * 16;
    const float* var = v_att + q * 16;
    const float* pr  = projAll + (size_t)nbk * PSTRIDE + 64 + q * 16;

    float part = 0.f;
#pragma unroll
    for (int j = 0; j < 16; j += 4) {
        float4 npv = *(const float4*)(npr + j);
        float4 vav = *(const float4*)(var + j);
        float4 pv  = *(const float4*)(pr + j);
        float x;
        x = npv.x + pv.x; x = fmaxf(x, 0.01f * x); part = fmaf(x, vav.x, part);
        x = npv.y + pv.y; x = fmaxf(x, 0.01f * x); part = fmaf(x, vav.y, part);
        x = npv.z + pv.z; x = fmaxf(x, 0.01f * x); part = fmaf(x, vav.z, part);
        x = npv.w + pv.w; x = fmaxf(x, 0.01f * x); part = fmaf(x, vav.w, part);
    }
    part += __shfl_xor(part, 16);
    part += __shfl_xor(part, 32);
    float pre = part + mk;

    float mp = pre, mw = wv;
#pragma unroll
    for (int off = 8; off >= 1; off >>= 1) {
        mp = fmaxf(mp, __shfl_xor(mp, off));
        mw = fmaxf(mw, __shfl_xor(mw, off));
    }
    float ep = __expf(pre - mp), ew = __expf(wv - mw);
    float sp = ep, sw = ew;
#pragma unroll
    for (int off = 8; off >= 1; off >>= 1) {
        sp += __shfl_xor(sp, off);
        sw += __shfl_xor(sw, off);
    }
    float att = (ep / sp) * (ew / sw);

    int half = lane >> 5, li = lane & 31;
    float ax = 0.f, ay = 0.f, az = 0.f, aw = 0.f;
#pragma unroll
    for (int m = 0; m < 8; ++m) {
        int src = 2 * m + half;
        int nb   = __shfl(nbk, src);
        float ak = __shfl(att, src);
        float4 e = *(const float4*)&Wc[(size_t)nb * D + 4 * li];
        ax = fmaf(e.x, ak, ax); ay = fmaf(e.y, ak, ay);
        az = fmaf(e.z, ak, az); aw = fmaf(e.w, ak, aw);
    }
    ax += __shfl_xor(ax, 32); ay += __shfl_xor(ay, 32);
    az += __shfl_xor(az, 32); aw += __shfl_xor(aw, 32);
    if (half == 0) {
        float4 o = make_float4(ax, ay, az, aw);
        *(float4*)&tmp[(size_t)n * D + 4 * li] = o;
    }
}

// claims for ALL levels in one pass (depends only on nodes input)
__global__ void amax3_kernel(const int* __restrict__ nodes, int* __restrict__ claims, int total) {
    int i = blockIdx.x * 256 + threadIdx.x;
    if (i < total) {
        int lvl = i / NN, pos = i - lvl * NN;
        atomicMax(&claims[(size_t)lvl * V + nodes[i]], pos);
    }
}

extern "C" void kernel_launch(void* const* d_in, const int* in_sizes, int n_in,
                              void* d_out, int out_size, void* d_ws, size_t ws_size,
                              hipStream_t stream) {
    const float* Leaf    = (const float*)d_in[0];
    const int*   nodes   = (const int*)d_in[1];
    const int*   neigh   = (const int*)d_in[2];
    const float* masks   = (const float*)d_in[3];
    const float* weights = (const float*)d_in[4];
    const float* Watt    = (const float*)d_in[5];
    const float* batt    = (const float*)d_in[6];
    const float* vatt    = (const float*)d_in[7];
    float* out = (float*)d_out;

    char* ws = (char*)d_ws;
    float* projAll = (float*)ws;                                      // V*128
    float* tmp     = (float*)(ws + (size_t)V * PSTRIDE * 4);          // NN*D
    int*   claims  = (int*)(ws + (size_t)(V * PSTRIDE + NN * D) * 4); // LVLS*V

    hipMemsetAsync(claims, 0xFF, (size_t)LVLS * V * sizeof(int), stream);  // -1
    amax3_kernel<<<(LVLS * NN + 255) / 256, 256, 0, stream>>>(nodes, claims, LVLS * NN);
    // one pass over Leaf: out copy + BOTH projection halves for all V rows
    projall_kernel<<<(V + TM - 1) / TM, 256, 0, stream>>>(Leaf, Watt, batt, projAll, out);

    for (int l = 0; l < LVLS; ++l) {
        const int* nodes_l = nodes + l * NN;
        attn_kernel<<<NN / 4, 256, 0, stream>>>(out, projAll, nodes_l,
                                                neigh + (size_t)l * NN * KK,
                                                masks + (size_t)l * NN * KK,
                                                weights + (size_t)l * NN * KK, vatt, tmp);
        commit_kernel<<<(NN + 31) / 32, 256, 0, stream>>>(
            tmp, Watt + (size_t)D * A, nodes_l, claims + (size_t)l * V, out, projAll,
            (l + 1 < LVLS) ? 1 : 0);
    }
}